// Round 11
// baseline (347.676 us; speedup 1.0000x reference)
//
#include <hip/hip_runtime.h>
#include <hip/hip_bf16.h>
#include <math.h>

#define TQ    1056
#define TKV   1088

typedef __attribute__((ext_vector_type(8))) short short8;
typedef __attribute__((ext_vector_type(4))) short short4v;
typedef __attribute__((ext_vector_type(4))) float float4v;
typedef unsigned short ushort_t;

__device__ inline ushort_t f2bf(float x){
  union{float f; unsigned u;} v; v.f = x;
  unsigned r = v.u + 0x7fff + ((v.u >> 16) & 1);
  return (ushort_t)(r >> 16);
}
__device__ inline float bf2f(ushort_t h){
  union{unsigned u; float f;} v; v.u = ((unsigned)h) << 16;
  return v.f;
}

// ---------------------------------------------------------------------------
// Fused f32 -> bf16 conversion (8 segments) + w_dw transpose tail blocks.
// ---------------------------------------------------------------------------
struct Cvt9 {
  const float* s[8];
  ushort_t*    d[8];
  const float* wdw;    // [512][31]
  float*       wdwT;   // [31][512]
  int bstart[9];
};

__global__ __launch_bounds__(256)
void cvt_f32_bf16(Cvt9 a)
{
  int blk = blockIdx.x;
  if (blk >= a.bstart[8]){
    int k = blk - a.bstart[8];
    int c = threadIdx.x;
    a.wdwT[k * 512 + c]       = a.wdw[c * 31 + k];
    a.wdwT[k * 512 + c + 256] = a.wdw[(c + 256) * 31 + k];
    return;
  }
  int seg = 0;
  while (blk >= a.bstart[seg + 1]) ++seg;
  int local = blk - a.bstart[seg];
  int idx = (local * 256 + threadIdx.x) * 4;
  float4v v = *(const float4v*)(a.s[seg] + idx);
  short4v o;
  #pragma unroll
  for (int j = 0; j < 4; ++j) ((ushort_t*)&o)[j] = f2bf(v[j]);
  *(short4v*)(a.d[seg] + idx) = o;
}

// ---------------------------------------------------------------------------
// Zero-LDS bf16 GEMM (attn-v4 style): all MFMA fragments loaded directly
// from global (16B/lane, L1/L2-served), no barriers, no LDS.
// K=512, tile 128 x NT, wave = 64m x (NT/2)n. XCD-partitioned grid.
// MODE 4: fused qkv (NT=128, N=1536) -> q_h(*0.125)/k_h/v_h
// MODE 0: outproj (NT=64) -> bf16 U0
// MODE 3: pw2 (NT=64) + bf16 resid -> f32 C0
// ---------------------------------------------------------------------------
template<int MODE, int NX, int NT>
__global__ __launch_bounds__(256)
void gemm_bf16(const ushort_t* __restrict__ A, const ushort_t* __restrict__ Wb,
               const float* __restrict__ bias, const float* __restrict__ bias2,
               const ushort_t* __restrict__ residb,
               float* __restrict__ C0, ushort_t* __restrict__ U0,
               ushort_t* __restrict__ U1, ushort_t* __restrict__ Uv, int ny)
{
  constexpr int JN = NT / 32;
  const int blk = blockIdx.x;
  const int xcd = blk & 7;
  const int j   = blk >> 3;
  const int n_idx = j % NX;
  const int m_idx = (j / NX) * 8 + xcd;
  if (m_idx >= ny) return;

  const int tid  = threadIdx.x;
  const int w    = tid >> 6;
  const int lane = tid & 63;
  const int quad = lane >> 4;
  const int l16  = lane & 15;
  const int n0 = n_idx * NT;
  const int m0 = m_idx * 128;
  const int wm = (w >> 1) * 64;
  const int wn = (w & 1) * (NT / 2);

  float4v acc[4][JN];
  #pragma unroll
  for (int i = 0; i < 4; ++i)
    #pragma unroll
    for (int jj = 0; jj < JN; ++jj)
      acc[i][jj] = (float4v)(0.f);

  const ushort_t* Ab = A  + (size_t)(m0 + wm + l16) * 512 + quad * 8;
  const ushort_t* Bb = Wb + (size_t)(n0 + wn + l16) * 512 + quad * 8;

  #pragma unroll 2
  for (int kt = 0; kt < 16; ++kt){
    const int k0 = kt * 32;
    short8 af[4], bf[JN];
    #pragma unroll
    for (int i = 0; i < 4; ++i)
      af[i] = *(const short8*)(Ab + (size_t)(i*16) * 512 + k0);
    #pragma unroll
    for (int jj = 0; jj < JN; ++jj)
      bf[jj] = *(const short8*)(Bb + (size_t)(jj*16) * 512 + k0);
    #pragma unroll
    for (int i = 0; i < 4; ++i)
      #pragma unroll
      for (int jj = 0; jj < JN; ++jj)
        acc[i][jj] = __builtin_amdgcn_mfma_f32_16x16x32_bf16(
                        af[i], bf[jj], acc[i][jj], 0, 0, 0);
  }

  #pragma unroll
  for (int jj = 0; jj < JN; ++jj){
    const int n = n0 + wn + jj*16 + l16;
    const float bn = (MODE == 4) ? (n < 512 ? bias[n] : bias2[(n - 512) & 1023])
                                 : bias[n];
    #pragma unroll
    for (int i = 0; i < 4; ++i){
      #pragma unroll
      for (int reg = 0; reg < 4; ++reg){
        const int m = m0 + wm + i*16 + quad*4 + reg;
        float v = acc[i][jj][reg] + bn;
        if (MODE == 4){
          int t = m >> 3, b = m & 7;
          if (n < 512){
            if (m >= 256){
              int mq = m - 256;
              int tq = mq >> 3, bq = mq & 7;
              int h = n >> 6, dh = n & 63;
              U0[(((size_t)(bq*8 + h)) * TQ + tq) * 64 + dh] = f2bf(v * 0.125f);
            }
          } else {
            int n2 = n & 511;
            int h = n2 >> 6, dh = n2 & 63;
            ushort_t* dst = (n < 1024) ? U1 : Uv;
            dst[(((size_t)(b*8 + h)) * TKV + t) * 64 + dh] = f2bf(v);
          }
        } else if (MODE == 0){
          U0[(size_t)m * 512 + n] = f2bf(v);
        } else {
          v += bf2f(residb[(size_t)m * 512 + n]);
          C0[(size_t)m * 512 + n] = v;
        }
      }
    }
  }
}

// ---------------------------------------------------------------------------
// Zero-LDS pw1 + GLU fused: tile 128m x (64a + 64g), direct fragment loads.
// ---------------------------------------------------------------------------
__global__ __launch_bounds__(256)
void gemm_pw1_glu(const ushort_t* __restrict__ A, const ushort_t* __restrict__ Wb,
                  const float* __restrict__ bias, ushort_t* __restrict__ G, int ny)
{
  const int blk = blockIdx.x;
  const int xcd = blk & 7;
  const int j   = blk >> 3;
  const int n_idx = j % 8;
  const int m_idx = (j / 8) * 8 + xcd;
  if (m_idx >= ny) return;

  const int tid  = threadIdx.x;
  const int w    = tid >> 6;
  const int lane = tid & 63;
  const int quad = lane >> 4;
  const int l16  = lane & 15;
  const int n0 = n_idx * 64;
  const int m0 = m_idx * 128;
  const int wm = (w >> 1) * 64;
  const int wn = (w & 1) * 32;

  float4v acca[4][2], accg[4][2];
  #pragma unroll
  for (int i = 0; i < 4; ++i)
    #pragma unroll
    for (int jj = 0; jj < 2; ++jj){
      acca[i][jj] = (float4v)(0.f);
      accg[i][jj] = (float4v)(0.f);
    }

  const ushort_t* Ab  = A  + (size_t)(m0 + wm + l16) * 512 + quad * 8;
  const ushort_t* Bab = Wb + (size_t)(n0 + wn + l16) * 512 + quad * 8;
  const ushort_t* Bgb = Bab + (size_t)512 * 512;

  #pragma unroll 2
  for (int kt = 0; kt < 16; ++kt){
    const int k0 = kt * 32;
    short8 af[4], ba[2], bg[2];
    #pragma unroll
    for (int i = 0; i < 4; ++i)
      af[i] = *(const short8*)(Ab + (size_t)(i*16) * 512 + k0);
    #pragma unroll
    for (int jj = 0; jj < 2; ++jj){
      ba[jj] = *(const short8*)(Bab + (size_t)(jj*16) * 512 + k0);
      bg[jj] = *(const short8*)(Bgb + (size_t)(jj*16) * 512 + k0);
    }
    #pragma unroll
    for (int i = 0; i < 4; ++i)
      #pragma unroll
      for (int jj = 0; jj < 2; ++jj){
        acca[i][jj] = __builtin_amdgcn_mfma_f32_16x16x32_bf16(
                         af[i], ba[jj], acca[i][jj], 0, 0, 0);
        accg[i][jj] = __builtin_amdgcn_mfma_f32_16x16x32_bf16(
                         af[i], bg[jj], accg[i][jj], 0, 0, 0);
      }
  }

  #pragma unroll
  for (int jj = 0; jj < 2; ++jj){
    const int n = n0 + wn + jj*16 + l16;
    const float bna = bias[n];
    const float bng = bias[n + 512];
    #pragma unroll
    for (int i = 0; i < 4; ++i){
      #pragma unroll
      for (int reg = 0; reg < 4; ++reg){
        const int m = m0 + wm + i*16 + quad*4 + reg;
        float a = acca[i][jj][reg] + bna;
        float g = accg[i][jj][reg] + bng;
        G[(size_t)m * 512 + n] = f2bf(a * (1.f / (1.f + __expf(-g))));
      }
    }
  }
}

// ---------------------------------------------------------------------------
// v_h [bh][t][dh] -> v_t [bh][dh][t] via LDS tile. Grid (17, 64).
// ---------------------------------------------------------------------------
__global__ __launch_bounds__(256)
void transpose_v(const ushort_t* __restrict__ vh, ushort_t* __restrict__ vt)
{
  const int t0 = blockIdx.x * 64;
  const int bh = blockIdx.y;
  const int tid = threadIdx.x;
  __shared__ __align__(16) ushort_t T[64 * 72];

  #pragma unroll
  for (int e = 0; e < 2; ++e){
    int idx = e * 256 + tid;
    int r = idx >> 3, sg = (idx & 7) * 8;
    *(short8*)&T[r * 72 + sg] =
        *(const short8*)&vh[(((size_t)bh) * TKV + t0 + r) * 64 + sg];
  }
  __syncthreads();

  const int dh = tid & 63;
  const int ts = (tid >> 6) * 16;
  short8 v0, v1;
  #pragma unroll
  for (int j = 0; j < 8; ++j){
    ((ushort_t*)&v0)[j] = T[(ts + j) * 72 + dh];
    ((ushort_t*)&v1)[j] = T[(ts + 8 + j) * 72 + dh];
  }
  const size_t ob = (((size_t)bh) * 64 + dh) * TKV + t0 + ts;
  *(short8*)&vt[ob]     = v0;
  *(short8*)&vt[ob + 8] = v1;
}

// ---------------------------------------------------------------------------
// MFMA attention v4 (unchanged): zero staging, LDS = P round-trip only.
// ---------------------------------------------------------------------------
#define PSTR 136

__global__ __launch_bounds__(256)
void attn_mfma(const ushort_t* __restrict__ qh, const ushort_t* __restrict__ kh,
               const ushort_t* __restrict__ vt, const int* __restrict__ lengths,
               ushort_t* __restrict__ attn_out)
{
  const int c  = blockIdx.x;
  const int bh = blockIdx.y;
  const int b  = bh >> 3, h = bh & 7;
  const int tid = threadIdx.x;
  const int w   = tid >> 6;
  const int lane = tid & 63;
  const int quad = lane >> 4;
  const int l16  = lane & 15;
  const int len  = lengths[b];
  const int tb2 = 64 + (c > 0 ? c - 1 : 0) * 32;
  const int tb3 = 64 + c * 32;

  __shared__ __align__(16) ushort_t Ps[48 * PSTR];

  const int basew = (w == 0) ? 0 : (w == 1) ? 32 : (w == 2) ? tb2 : tb3;

  float4v Sf[3][2];
  #pragma unroll
  for (int mt = 0; mt < 3; ++mt)
    #pragma unroll
    for (int jt = 0; jt < 2; ++jt)
      Sf[mt][jt] = (float4v)(0.f);

  #pragma unroll
  for (int kc = 0; kc < 2; ++kc){
    short8 bfr[2];
    #pragma unroll
    for (int jt = 0; jt < 2; ++jt)
      bfr[jt] = *(const short8*)&kh[((size_t)bh * TKV + basew + jt*16 + l16) * 64
                                    + kc*32 + quad*8];
    #pragma unroll
    for (int mt = 0; mt < 3; ++mt){
      int trow = (mt == 0) ? c : 32 + c*32 + (mt-1)*16 + l16;
      short8 afr = *(const short8*)&qh[((size_t)bh * TQ + trow) * 64
                                       + kc*32 + quad*8];
      if (mt == 0 && l16 != 0){
        short8 z = {0,0,0,0,0,0,0,0};
        afr = z;
      }
      #pragma unroll
      for (int jt = 0; jt < 2; ++jt)
        Sf[mt][jt] = __builtin_amdgcn_mfma_f32_16x16x32_bf16(
                        afr, bfr[jt], Sf[mt][jt], 0, 0, 0);
    }
  }

  bool live[2];
  #pragma unroll
  for (int jt = 0; jt < 2; ++jt){
    int jcol = jt*16 + l16;
    if      (w == 0) live[jt] = (jcol < c);
    else if (w == 1) live[jt] = (jcol == c);
    else if (w == 2) live[jt] = (c > 0) && ((c-1)*32 + jcol < len);
    else             live[jt] = (c*32 + jcol < len);
  }
  #pragma unroll
  for (int mt = 0; mt < 3; ++mt)
    #pragma unroll
    for (int jt = 0; jt < 2; ++jt)
      #pragma unroll
      for (int r = 0; r < 4; ++r){
        int row = mt*16 + quad*4 + r;
        Ps[row * PSTR + w*32 + jt*16 + l16] =
            live[jt] ? f2bf(__expf(Sf[mt][jt][r])) : (ushort_t)0;
      }
  __syncthreads();

  const short8 ones = {0x3F80,0x3F80,0x3F80,0x3F80,0x3F80,0x3F80,0x3F80,0x3F80};
  float4v Of[3], Ls[3];
  #pragma unroll
  for (int mt = 0; mt < 3; ++mt){ Of[mt] = (float4v)(0.f); Ls[mt] = (float4v)(0.f); }
  #pragma unroll
  for (int kc = 0; kc < 4; ++kc){
    const int tbase = (kc == 0) ? 0 : (kc == 1) ? 32 : (kc == 2) ? tb2 : tb3;
    short8 bv = *(const short8*)&vt[((size_t)bh * 64 + w*16 + l16) * TKV
                                    + tbase + quad*8];
    #pragma unroll
    for (int mt = 0; mt < 3; ++mt){
      short8 ap = *(const short8*)&Ps[(mt*16 + l16) * PSTR + kc*32 + quad*8];
      Of[mt] = __builtin_amdgcn_mfma_f32_16x16x32_bf16(ap, bv,   Of[mt], 0,0,0);
      Ls[mt] = __builtin_amdgcn_mfma_f32_16x16x32_bf16(ap, ones, Ls[mt], 0,0,0);
    }
  }

  #pragma unroll
  for (int mt = 0; mt < 3; ++mt){
    #pragma unroll
    for (int r = 0; r < 4; ++r){
      int row = mt*16 + quad*4 + r;
      if (mt == 0 && row != 0) continue;
      float o = Of[mt][r] / Ls[mt][r];
      int t = (mt == 0) ? c : 32 + c*32 + (row - 16);
      attn_out[(((size_t)t) * 8 + b) * 512 + h*64 + w*16 + l16] = f2bf(o);
    }
  }
}

// ---------------------------------------------------------------------------
// Depthwise conv(31) + LN + SiLU. Input-centric conv: each staged value is
// read from LDS ONCE and scattered into the 16 accumulators (register-light).
// ---------------------------------------------------------------------------
__global__ __launch_bounds__(512)
void conv_ln_silu4(const ushort_t* __restrict__ glub,
                   const float* __restrict__ w_dwT, const float* __restrict__ b_dw,
                   const float* __restrict__ ln_g, const float* __restrict__ ln_b,
                   ushort_t* __restrict__ zb)
{
  const int b  = blockIdx.y;
  const int t0 = blockIdx.x * 16;
  const int tid = threadIdx.x;
  __shared__ __align__(16) char smem[47104];
  ushort_t* in_t = (ushort_t*)smem;
  float*    S    = (float*)smem;

  for (int e = tid; e < 2944; e += 512){
    int row = e >> 6, sg = (e & 63) * 8;
    int tt = t0 - 15 + row;
    short8 v = {0,0,0,0,0,0,0,0};
    if (tt >= 0 && tt < TQ)
      v = *(const short8*)&glub[((size_t)tt * 8 + b) * 512 + sg];
    *(short8*)&in_t[row * 512 + sg] = v;
  }
  float wreg[31];
  #pragma unroll
  for (int k = 0; k < 31; ++k) wreg[k] = w_dwT[k * 512 + tid];
  const float bd = b_dw[tid];
  __syncthreads();

  float r[16];
  #pragma unroll
  for (int t = 0; t < 16; ++t) r[t] = bd;

  // out[t] = bd + sum_k in[t+k]*w[k]; input row rr feeds t in [rr-30, rr]
  #pragma unroll
  for (int rr = 0; rr < 46; ++rr){
    float v = bf2f(in_t[rr * 512 + tid]);
    const int tlo = (rr > 30) ? rr - 30 : 0;
    const int thi = (rr < 15) ? rr : 15;
    #pragma unroll
    for (int t = 0; t < 16; ++t)
      if (t >= tlo && t <= thi)
        r[t] += v * wreg[rr - t];
  }
  __syncthreads();
  #pragma unroll
  for (int t = 0; t < 16; ++t) S[t * 512 + tid] = r[t];
  __syncthreads();

  const int tg = tid >> 5;
  const int l  = tid & 31;
  float s = 0.f;
  #pragma unroll
  for (int i = 0; i < 16; ++i) s += S[tg * 512 + l + 32*i];
  #pragma unroll
  for (int off = 16; off >= 1; off >>= 1) s += __shfl_xor(s, off);
  const float mu = s * (1.f / 512.f);
  float s2 = 0.f;
  #pragma unroll
  for (int i = 0; i < 16; ++i){
    float d = S[tg * 512 + l + 32*i] - mu;
    s2 += d * d;
  }
  #pragma unroll
  for (int off = 16; off >= 1; off >>= 1) s2 += __shfl_xor(s2, off);
  const float rs = rsqrtf(s2 * (1.f / 512.f) + 1e-5f);

  const int c0 = l * 16;
  ushort_t ov[16];
  #pragma unroll
  for (int e = 0; e < 4; ++e){
    float4v xv = *(const float4v*)&S[tg * 512 + c0 + e*4];
    float4v gv = *(const float4v*)&ln_g[c0 + e*4];
    float4v bv = *(const float4v*)&ln_b[c0 + e*4];
    #pragma unroll
    for (int jj = 0; jj < 4; ++jj){
      float xn = (xv[jj] - mu) * rs * gv[jj] + bv[jj];
      ov[e*4 + jj] = f2bf(xn * (1.f / (1.f + __expf(-xn))));
    }
  }
  const size_t obase = ((size_t)(t0 + tg) * 8 + b) * 512 + c0;
  *(short8*)&zb[obase]     = *(short8*)&ov[0];
  *(short8*)&zb[obase + 8] = *(short8*)&ov[8];
}

// ---------------------------------------------------------------------------
extern "C" void kernel_launch(void* const* d_in, const int* in_sizes, int n_in,
                              void* d_out, int out_size, void* d_ws, size_t ws_size,
                              hipStream_t stream)
{
  (void)in_sizes; (void)n_in; (void)out_size; (void)ws_size;
  const float* utter = (const float*)d_in[0];
  const float* rctx  = (const float*)d_in[1];
  const float* memry = (const float*)d_in[3];
  const float* b_q   = (const float*)d_in[5];
  const float* b_kv  = (const float*)d_in[7];
  const float* b_out = (const float*)d_in[9];
  const float* b_pw1 = (const float*)d_in[11];
  const float* w_dw  = (const float*)d_in[12];
  const float* b_dw  = (const float*)d_in[13];
  const float* ln_g  = (const float*)d_in[14];
  const float* ln_b  = (const float*)d_in[15];
  const float* b_pw2 = (const float*)d_in[17];
  const int* lengths = (const int*)d_in[18];

  ushort_t* u = (ushort_t*)d_ws;
  ushort_t* memB  = u;                    // 131072
  ushort_t* rcB   = memB  + 131072;       // 131072
  ushort_t* uttB  = rcB   + 131072;       // 4194304
  ushort_t* wqB   = uttB  + 4194304;      // 262144 (wq; wkv adjacent)
  ushort_t* wkvB  = wqB   + 262144;       // 524288
  ushort_t* woutB = wkvB  + 524288;       // 262144
  ushort_t* wpw1B = woutB + 262144;       // 524288
  ushort_t* wpw2B = wpw1B + 524288;       // 262144
  ushort_t* q_h   = wpw2B + 262144;       // 4325376
  ushort_t* k_h   = q_h   + 4325376;      // 4456448
  ushort_t* v_h   = k_h   + 4456448;      // 4456448
  ushort_t* v_t   = v_h   + 4456448;      // 4456448
  ushort_t* attnb = v_t   + 4456448;      // 4325376
  ushort_t* outru_bf = attnb + 4325376;   // 4325376
  float*    wdwT  = (float*)(outru_bf + 4325376);   // 15872 f32
  ushort_t* glub  = q_h;                  // reuse q_h (dead after attn)
  ushort_t* zb    = attnb;                // reuse attnb (dead after out-proj)
  float* outp = (float*)d_out;

  const ushort_t* A_kv = memB;   // [mem | rc | utt] = 8704 rows

  Cvt9 ca;
  ca.s[0] = memry;                 ca.d[0] = memB;
  ca.s[1] = rctx;                  ca.d[1] = rcB;
  ca.s[2] = utter;                 ca.d[2] = uttB;
  ca.s[3] = (const float*)d_in[4]; ca.d[3] = wqB;
  ca.s[4] = (const float*)d_in[6]; ca.d[4] = wkvB;
  ca.s[5] = (const float*)d_in[8]; ca.d[5] = woutB;
  ca.s[6] = (const float*)d_in[10];ca.d[6] = wpw1B;
  ca.s[7] = (const float*)d_in[16];ca.d[7] = wpw2B;
  ca.wdw = w_dw; ca.wdwT = wdwT;
  int cnt[8] = {131072,131072,4194304,262144,524288,262144,524288,262144};
  int acc = 0;
  for (int i = 0; i < 8; ++i){ ca.bstart[i] = acc; acc += cnt[i] / 1024; }
  ca.bstart[8] = acc;
  cvt_f32_bf16<<<dim3(acc + 31), 256, 0, stream>>>(ca);

  // 1. fused qkv projection (N=1536, M=8704, NT=128) -> q_h / k_h / v_h
  gemm_bf16<4, 12, 128><<<dim3(8 * 9 * 12), 256, 0, stream>>>(
      A_kv, wqB, b_q, b_kv, nullptr, nullptr, q_h, k_h, v_h, 68);
  // 2. v transpose -> v_t [bh][dh][t]
  transpose_v<<<dim3(17, 64), 256, 0, stream>>>(v_h, v_t);
  // 3. attention (zero-staging) -> bf16 attnb
  attn_mfma<<<dim3(32, 64), 256, 0, stream>>>(q_h, k_h, v_t, lengths, attnb);
  // 4. out projection (NT=64) -> bf16 outru_bf
  gemm_bf16<0, 8, 64><<<dim3(8 * 9 * 8), 256, 0, stream>>>(
      attnb, woutB, b_out, nullptr, nullptr, nullptr, outru_bf, nullptr, nullptr, 66);
  // 5. pw1 + GLU -> bf16 glub
  gemm_pw1_glu<<<dim3(8 * 9 * 8), 256, 0, stream>>>(outru_bf, wpw1B, b_pw1, glub, 66);
  // 6. depthwise conv + LN + SiLU -> bf16 zb
  conv_ln_silu4<<<dim3(66, 8), 512, 0, stream>>>(glub, wdwT, b_dw, ln_g, ln_b, zb);
  // 7. pw2 + bf16 residual -> f32 out
  gemm_bf16<3, 8, 64><<<dim3(8 * 9 * 8), 256, 0, stream>>>(
      zb, wpw2B, b_pw2, nullptr, outru_bf, outp, nullptr, nullptr, nullptr, 66);
}

// Round 12
// 235.570 us; speedup vs baseline: 1.4759x; 1.4759x over previous
//
#include <hip/hip_runtime.h>
#include <hip/hip_bf16.h>
#include <math.h>

#define TQ    1056
#define TKV   1088

typedef __attribute__((ext_vector_type(8))) short short8;
typedef __attribute__((ext_vector_type(4))) short short4v;
typedef __attribute__((ext_vector_type(4))) float float4v;
typedef unsigned short ushort_t;

__device__ inline ushort_t f2bf(float x){
  union{float f; unsigned u;} v; v.f = x;
  unsigned r = v.u + 0x7fff + ((v.u >> 16) & 1);
  return (ushort_t)(r >> 16);
}
__device__ inline float bf2f(ushort_t h){
  union{unsigned u; float f;} v; v.u = ((unsigned)h) << 16;
  return v.f;
}

__device__ inline void gl_lds16(const ushort_t* g, ushort_t* l){
  __builtin_amdgcn_global_load_lds(
      (const __attribute__((address_space(1))) unsigned int*)g,
      (__attribute__((address_space(3))) unsigned int*)l, 16, 0, 0);
}

// ---------------------------------------------------------------------------
// Fused f32 -> bf16 conversion (8 segments) + w_dw transpose tail blocks.
// ---------------------------------------------------------------------------
struct Cvt9 {
  const float* s[8];
  ushort_t*    d[8];
  const float* wdw;    // [512][31]
  float*       wdwT;   // [31][512]
  int bstart[9];
};

__global__ __launch_bounds__(256)
void cvt_f32_bf16(Cvt9 a)
{
  int blk = blockIdx.x;
  if (blk >= a.bstart[8]){
    int k = blk - a.bstart[8];
    int c = threadIdx.x;
    a.wdwT[k * 512 + c]       = a.wdw[c * 31 + k];
    a.wdwT[k * 512 + c + 256] = a.wdw[(c + 256) * 31 + k];
    return;
  }
  int seg = 0;
  while (blk >= a.bstart[seg + 1]) ++seg;
  int local = blk - a.bstart[seg];
  int idx = (local * 256 + threadIdx.x) * 4;
  float4v v = *(const float4v*)(a.s[seg] + idx);
  short4v o;
  #pragma unroll
  for (int j = 0; j < 4; ++j) ((ushort_t*)&o)[j] = f2bf(v[j]);
  *(short4v*)(a.d[seg] + idx) = o;
}

// ---------------------------------------------------------------------------
// bf16 GEMM, K=512, BK=64, tile 128 x NT, XOR-swizzled global_load_lds
// staging (0 bank conflicts), XCD-partitioned grid.  [round-10 proven]
// MODE 4: fused qkv (NT=128, N=1536) -> q_h(*0.125)/k_h/v_h
// MODE 0: outproj -> bf16 U0
// MODE 3: pw2 + bf16 resid -> f32 C0
// ---------------------------------------------------------------------------
template<int MODE, int NX, int NT>
__global__ __launch_bounds__(256)
void gemm_bf16(const ushort_t* __restrict__ A, const ushort_t* __restrict__ Wb,
               const float* __restrict__ bias, const float* __restrict__ bias2,
               const ushort_t* __restrict__ residb,
               float* __restrict__ C0, ushort_t* __restrict__ U0,
               ushort_t* __restrict__ U1, ushort_t* __restrict__ Uv, int ny)
{
  constexpr int JN = NT / 32;
  const int blk = blockIdx.x;
  const int xcd = blk & 7;
  const int j   = blk >> 3;
  const int n_idx = j % NX;
  const int m_idx = (j / NX) * 8 + xcd;
  if (m_idx >= ny) return;

  __shared__ __align__(16) ushort_t As[128 * 64];
  __shared__ __align__(16) ushort_t Bs[NT * 64];
  const int tid  = threadIdx.x;
  const int w    = tid >> 6;
  const int lane = tid & 63;
  const int quad = lane >> 4;
  const int l16  = lane & 15;
  const int n0 = n_idx * NT;
  const int m0 = m_idx * 128;
  const int wm = (w >> 1) * 64;
  const int wn = (w & 1) * (NT / 2);
  const int srow = tid >> 3;
  const int skseg = tid & 7;

  float4v acc[4][JN];
  #pragma unroll
  for (int i = 0; i < 4; ++i)
    #pragma unroll
    for (int jj = 0; jj < JN; ++jj)
      acc[i][jj] = (float4v)(0.f);

  for (int kt = 0; kt < 8; ++kt){
    const int k0 = kt * 64;
    #pragma unroll
    for (int s = 0; s < 4; ++s){
      int row = s*32 + srow;
      gl_lds16(A + (size_t)(m0 + row) * 512 + k0 + ((skseg ^ (row & 7)) << 3),
               &As[row * 64 + (skseg << 3)]);
    }
    #pragma unroll
    for (int s = 0; s < NT/32; ++s){
      int row = s*32 + srow;
      gl_lds16(Wb + (size_t)(n0 + row) * 512 + k0 + ((skseg ^ (row & 7)) << 3),
               &Bs[row * 64 + (skseg << 3)]);
    }
    __syncthreads();
    #pragma unroll
    for (int kc = 0; kc < 2; ++kc){
      const int col = (((quad + (kc << 2)) ^ (l16 & 7)) << 3);
      short8 af[4], bf[JN];
      #pragma unroll
      for (int i = 0; i < 4; ++i)
        af[i] = *(const short8*)&As[(wm + i*16 + l16) * 64 + col];
      #pragma unroll
      for (int jj = 0; jj < JN; ++jj)
        bf[jj] = *(const short8*)&Bs[(wn + jj*16 + l16) * 64 + col];
      #pragma unroll
      for (int i = 0; i < 4; ++i)
        #pragma unroll
        for (int jj = 0; jj < JN; ++jj)
          acc[i][jj] = __builtin_amdgcn_mfma_f32_16x16x32_bf16(
                          af[i], bf[jj], acc[i][jj], 0, 0, 0);
    }
    __syncthreads();
  }

  #pragma unroll
  for (int jj = 0; jj < JN; ++jj){
    const int n = n0 + wn + jj*16 + l16;
    const float bn = (MODE == 4) ? (n < 512 ? bias[n] : bias2[(n - 512) & 1023])
                                 : bias[n];
    #pragma unroll
    for (int i = 0; i < 4; ++i){
      #pragma unroll
      for (int reg = 0; reg < 4; ++reg){
        const int m = m0 + wm + i*16 + quad*4 + reg;
        float v = acc[i][jj][reg] + bn;
        if (MODE == 4){
          int t = m >> 3, b = m & 7;
          if (n < 512){
            if (m >= 256){
              int mq = m - 256;
              int tq = mq >> 3, bq = mq & 7;
              int h = n >> 6, dh = n & 63;
              U0[(((size_t)(bq*8 + h)) * TQ + tq) * 64 + dh] = f2bf(v * 0.125f);
            }
          } else {
            int n2 = n & 511;
            int h = n2 >> 6, dh = n2 & 63;
            ushort_t* dst = (n < 1024) ? U1 : Uv;
            dst[(((size_t)(b*8 + h)) * TKV + t) * 64 + dh] = f2bf(v);
          }
        } else if (MODE == 0){
          U0[(size_t)m * 512 + n] = f2bf(v);
        } else {
          v += bf2f(residb[(size_t)m * 512 + n]);
          C0[(size_t)m * 512 + n] = v;
        }
      }
    }
  }
}

// ---------------------------------------------------------------------------
// pw1 + GLU fused: tile 128m x (64a + 64g), BK=64, swizzled staging.
// ---------------------------------------------------------------------------
__global__ __launch_bounds__(256)
void gemm_pw1_glu(const ushort_t* __restrict__ A, const ushort_t* __restrict__ Wb,
                  const float* __restrict__ bias, ushort_t* __restrict__ G, int ny)
{
  const int blk = blockIdx.x;
  const int xcd = blk & 7;
  const int j   = blk >> 3;
  const int n_idx = j % 8;
  const int m_idx = (j / 8) * 8 + xcd;
  if (m_idx >= ny) return;

  __shared__ __align__(16) ushort_t As [128 * 64];
  __shared__ __align__(16) ushort_t Bsa[64 * 64];
  __shared__ __align__(16) ushort_t Bsg[64 * 64];
  const int tid  = threadIdx.x;
  const int w    = tid >> 6;
  const int lane = tid & 63;
  const int quad = lane >> 4;
  const int l16  = lane & 15;
  const int n0 = n_idx * 64;
  const int m0 = m_idx * 128;
  const int wm = (w >> 1) * 64;
  const int wn = (w & 1) * 32;
  const int srow = tid >> 3;
  const int skseg = tid & 7;

  float4v acca[4][2], accg[4][2];
  #pragma unroll
  for (int i = 0; i < 4; ++i)
    #pragma unroll
    for (int jj = 0; jj < 2; ++jj){
      acca[i][jj] = (float4v)(0.f);
      accg[i][jj] = (float4v)(0.f);
    }

  for (int kt = 0; kt < 8; ++kt){
    const int k0 = kt * 64;
    #pragma unroll
    for (int s = 0; s < 4; ++s){
      int row = s*32 + srow;
      gl_lds16(A + (size_t)(m0 + row) * 512 + k0 + ((skseg ^ (row & 7)) << 3),
               &As[row * 64 + (skseg << 3)]);
    }
    #pragma unroll
    for (int s = 0; s < 2; ++s){
      int row = s*32 + srow;
      gl_lds16(Wb + (size_t)(n0 + row) * 512 + k0 + ((skseg ^ (row & 7)) << 3),
               &Bsa[row * 64 + (skseg << 3)]);
      gl_lds16(Wb + (size_t)(n0 + 512 + row) * 512 + k0 + ((skseg ^ (row & 7)) << 3),
               &Bsg[row * 64 + (skseg << 3)]);
    }
    __syncthreads();
    #pragma unroll
    for (int kc = 0; kc < 2; ++kc){
      const int col = (((quad + (kc << 2)) ^ (l16 & 7)) << 3);
      short8 af[4], ba[2], bg[2];
      #pragma unroll
      for (int i = 0; i < 4; ++i)
        af[i] = *(const short8*)&As[(wm + i*16 + l16) * 64 + col];
      #pragma unroll
      for (int jj = 0; jj < 2; ++jj){
        ba[jj] = *(const short8*)&Bsa[(wn + jj*16 + l16) * 64 + col];
        bg[jj] = *(const short8*)&Bsg[(wn + jj*16 + l16) * 64 + col];
      }
      #pragma unroll
      for (int i = 0; i < 4; ++i)
        #pragma unroll
        for (int jj = 0; jj < 2; ++jj){
          acca[i][jj] = __builtin_amdgcn_mfma_f32_16x16x32_bf16(
                           af[i], ba[jj], acca[i][jj], 0, 0, 0);
          accg[i][jj] = __builtin_amdgcn_mfma_f32_16x16x32_bf16(
                           af[i], bg[jj], accg[i][jj], 0, 0, 0);
        }
    }
    __syncthreads();
  }

  #pragma unroll
  for (int jj = 0; jj < 2; ++jj){
    const int n = n0 + wn + jj*16 + l16;
    const float bna = bias[n];
    const float bng = bias[n + 512];
    #pragma unroll
    for (int i = 0; i < 4; ++i){
      #pragma unroll
      for (int reg = 0; reg < 4; ++reg){
        const int m = m0 + wm + i*16 + quad*4 + reg;
        float a = acca[i][jj][reg] + bna;
        float g = accg[i][jj][reg] + bng;
        G[(size_t)m * 512 + n] = f2bf(a * (1.f / (1.f + __expf(-g))));
      }
    }
  }
}

// ---------------------------------------------------------------------------
// v_h [bh][t][dh] -> v_t [bh][dh][t] via LDS tile. Grid (17, 64).
// ---------------------------------------------------------------------------
__global__ __launch_bounds__(256)
void transpose_v(const ushort_t* __restrict__ vh, ushort_t* __restrict__ vt)
{
  const int t0 = blockIdx.x * 64;
  const int bh = blockIdx.y;
  const int tid = threadIdx.x;
  __shared__ __align__(16) ushort_t T[64 * 72];

  #pragma unroll
  for (int e = 0; e < 2; ++e){
    int idx = e * 256 + tid;
    int r = idx >> 3, sg = (idx & 7) * 8;
    *(short8*)&T[r * 72 + sg] =
        *(const short8*)&vh[(((size_t)bh) * TKV + t0 + r) * 64 + sg];
  }
  __syncthreads();

  const int dh = tid & 63;
  const int ts = (tid >> 6) * 16;
  short8 v0, v1;
  #pragma unroll
  for (int j = 0; j < 8; ++j){
    ((ushort_t*)&v0)[j] = T[(ts + j) * 72 + dh];
    ((ushort_t*)&v1)[j] = T[(ts + 8 + j) * 72 + dh];
  }
  const size_t ob = (((size_t)bh) * 64 + dh) * TKV + t0 + ts;
  *(short8*)&vt[ob]     = v0;
  *(short8*)&vt[ob + 8] = v1;
}

// ---------------------------------------------------------------------------
// MFMA attention v4: zero staging, LDS = P round-trip only. One barrier.
// ---------------------------------------------------------------------------
#define PSTR 136

__global__ __launch_bounds__(256)
void attn_mfma(const ushort_t* __restrict__ qh, const ushort_t* __restrict__ kh,
               const ushort_t* __restrict__ vt, const int* __restrict__ lengths,
               ushort_t* __restrict__ attn_out)
{
  const int c  = blockIdx.x;
  const int bh = blockIdx.y;
  const int b  = bh >> 3, h = bh & 7;
  const int tid = threadIdx.x;
  const int w   = tid >> 6;
  const int lane = tid & 63;
  const int quad = lane >> 4;
  const int l16  = lane & 15;
  const int len  = lengths[b];
  const int tb2 = 64 + (c > 0 ? c - 1 : 0) * 32;
  const int tb3 = 64 + c * 32;

  __shared__ __align__(16) ushort_t Ps[48 * PSTR];

  const int basew = (w == 0) ? 0 : (w == 1) ? 32 : (w == 2) ? tb2 : tb3;

  float4v Sf[3][2];
  #pragma unroll
  for (int mt = 0; mt < 3; ++mt)
    #pragma unroll
    for (int jt = 0; jt < 2; ++jt)
      Sf[mt][jt] = (float4v)(0.f);

  #pragma unroll
  for (int kc = 0; kc < 2; ++kc){
    short8 bfr[2];
    #pragma unroll
    for (int jt = 0; jt < 2; ++jt)
      bfr[jt] = *(const short8*)&kh[((size_t)bh * TKV + basew + jt*16 + l16) * 64
                                    + kc*32 + quad*8];
    #pragma unroll
    for (int mt = 0; mt < 3; ++mt){
      int trow = (mt == 0) ? c : 32 + c*32 + (mt-1)*16 + l16;
      short8 afr = *(const short8*)&qh[((size_t)bh * TQ + trow) * 64
                                       + kc*32 + quad*8];
      if (mt == 0 && l16 != 0){
        short8 z = {0,0,0,0,0,0,0,0};
        afr = z;
      }
      #pragma unroll
      for (int jt = 0; jt < 2; ++jt)
        Sf[mt][jt] = __builtin_amdgcn_mfma_f32_16x16x32_bf16(
                        afr, bfr[jt], Sf[mt][jt], 0, 0, 0);
    }
  }

  bool live[2];
  #pragma unroll
  for (int jt = 0; jt < 2; ++jt){
    int jcol = jt*16 + l16;
    if      (w == 0) live[jt] = (jcol < c);
    else if (w == 1) live[jt] = (jcol == c);
    else if (w == 2) live[jt] = (c > 0) && ((c-1)*32 + jcol < len);
    else             live[jt] = (c*32 + jcol < len);
  }
  #pragma unroll
  for (int mt = 0; mt < 3; ++mt)
    #pragma unroll
    for (int jt = 0; jt < 2; ++jt)
      #pragma unroll
      for (int r = 0; r < 4; ++r){
        int row = mt*16 + quad*4 + r;
        Ps[row * PSTR + w*32 + jt*16 + l16] =
            live[jt] ? f2bf(__expf(Sf[mt][jt][r])) : (ushort_t)0;
      }
  __syncthreads();

  const short8 ones = {0x3F80,0x3F80,0x3F80,0x3F80,0x3F80,0x3F80,0x3F80,0x3F80};
  float4v Of[3], Ls[3];
  #pragma unroll
  for (int mt = 0; mt < 3; ++mt){ Of[mt] = (float4v)(0.f); Ls[mt] = (float4v)(0.f); }
  #pragma unroll
  for (int kc = 0; kc < 4; ++kc){
    const int tbase = (kc == 0) ? 0 : (kc == 1) ? 32 : (kc == 2) ? tb2 : tb3;
    short8 bv = *(const short8*)&vt[((size_t)bh * 64 + w*16 + l16) * TKV
                                    + tbase + quad*8];
    #pragma unroll
    for (int mt = 0; mt < 3; ++mt){
      short8 ap = *(const short8*)&Ps[(mt*16 + l16) * PSTR + kc*32 + quad*8];
      Of[mt] = __builtin_amdgcn_mfma_f32_16x16x32_bf16(ap, bv,   Of[mt], 0,0,0);
      Ls[mt] = __builtin_amdgcn_mfma_f32_16x16x32_bf16(ap, ones, Ls[mt], 0,0,0);
    }
  }

  #pragma unroll
  for (int mt = 0; mt < 3; ++mt){
    #pragma unroll
    for (int r = 0; r < 4; ++r){
      int row = mt*16 + quad*4 + r;
      if (mt == 0 && row != 0) continue;
      float o = Of[mt][r] / Ls[mt][r];
      int t = (mt == 0) ? c : 32 + c*32 + (row - 16);
      attn_out[(((size_t)t) * 8 + b) * 512 + h*64 + w*16 + l16] = f2bf(o);
    }
  }
}

// ---------------------------------------------------------------------------
// Depthwise conv(31) + LN + SiLU. Input-centric conv (each LDS value read
// once, scattered into 16 accumulators).
// ---------------------------------------------------------------------------
__global__ __launch_bounds__(512)
void conv_ln_silu4(const ushort_t* __restrict__ glub,
                   const float* __restrict__ w_dwT, const float* __restrict__ b_dw,
                   const float* __restrict__ ln_g, const float* __restrict__ ln_b,
                   ushort_t* __restrict__ zb)
{
  const int b  = blockIdx.y;
  const int t0 = blockIdx.x * 16;
  const int tid = threadIdx.x;
  __shared__ __align__(16) char smem[47104];
  ushort_t* in_t = (ushort_t*)smem;
  float*    S    = (float*)smem;

  for (int e = tid; e < 2944; e += 512){
    int row = e >> 6, sg = (e & 63) * 8;
    int tt = t0 - 15 + row;
    short8 v = {0,0,0,0,0,0,0,0};
    if (tt >= 0 && tt < TQ)
      v = *(const short8*)&glub[((size_t)tt * 8 + b) * 512 + sg];
    *(short8*)&in_t[row * 512 + sg] = v;
  }
  float wreg[31];
  #pragma unroll
  for (int k = 0; k < 31; ++k) wreg[k] = w_dwT[k * 512 + tid];
  const float bd = b_dw[tid];
  __syncthreads();

  float r[16];
  #pragma unroll
  for (int t = 0; t < 16; ++t) r[t] = bd;

  #pragma unroll
  for (int rr = 0; rr < 46; ++rr){
    float v = bf2f(in_t[rr * 512 + tid]);
    const int tlo = (rr > 30) ? rr - 30 : 0;
    const int thi = (rr < 15) ? rr : 15;
    #pragma unroll
    for (int t = 0; t < 16; ++t)
      if (t >= tlo && t <= thi)
        r[t] += v * wreg[rr - t];
  }
  __syncthreads();
  #pragma unroll
  for (int t = 0; t < 16; ++t) S[t * 512 + tid] = r[t];
  __syncthreads();

  const int tg = tid >> 5;
  const int l  = tid & 31;
  float s = 0.f;
  #pragma unroll
  for (int i = 0; i < 16; ++i) s += S[tg * 512 + l + 32*i];
  #pragma unroll
  for (int off = 16; off >= 1; off >>= 1) s += __shfl_xor(s, off);
  const float mu = s * (1.f / 512.f);
  float s2 = 0.f;
  #pragma unroll
  for (int i = 0; i < 16; ++i){
    float d = S[tg * 512 + l + 32*i] - mu;
    s2 += d * d;
  }
  #pragma unroll
  for (int off = 16; off >= 1; off >>= 1) s2 += __shfl_xor(s2, off);
  const float rs = rsqrtf(s2 * (1.f / 512.f) + 1e-5f);

  const int c0 = l * 16;
  ushort_t ov[16];
  #pragma unroll
  for (int e = 0; e < 4; ++e){
    float4v xv = *(const float4v*)&S[tg * 512 + c0 + e*4];
    float4v gv = *(const float4v*)&ln_g[c0 + e*4];
    float4v bv = *(const float4v*)&ln_b[c0 + e*4];
    #pragma unroll
    for (int jj = 0; jj < 4; ++jj){
      float xn = (xv[jj] - mu) * rs * gv[jj] + bv[jj];
      ov[e*4 + jj] = f2bf(xn * (1.f / (1.f + __expf(-xn))));
    }
  }
  const size_t obase = ((size_t)(t0 + tg) * 8 + b) * 512 + c0;
  *(short8*)&zb[obase]     = *(short8*)&ov[0];
  *(short8*)&zb[obase + 8] = *(short8*)&ov[8];
}

// ---------------------------------------------------------------------------
extern "C" void kernel_launch(void* const* d_in, const int* in_sizes, int n_in,
                              void* d_out, int out_size, void* d_ws, size_t ws_size,
                              hipStream_t stream)
{
  (void)in_sizes; (void)n_in; (void)out_size; (void)ws_size;
  const float* utter = (const float*)d_in[0];
  const float* rctx  = (const float*)d_in[1];
  const float* memry = (const float*)d_in[3];
  const float* b_q   = (const float*)d_in[5];
  const float* b_kv  = (const float*)d_in[7];
  const float* b_out = (const float*)d_in[9];
  const float* b_pw1 = (const float*)d_in[11];
  const float* w_dw  = (const float*)d_in[12];
  const float* b_dw  = (const float*)d_in[13];
  const float* ln_g  = (const float*)d_in[14];
  const float* ln_b  = (const float*)d_in[15];
  const float* b_pw2 = (const float*)d_in[17];
  const int* lengths = (const int*)d_in[18];

  ushort_t* u = (ushort_t*)d_ws;
  ushort_t* memB  = u;                    // 131072
  ushort_t* rcB   = memB  + 131072;       // 131072
  ushort_t* uttB  = rcB   + 131072;       // 4194304
  ushort_t* wqB   = uttB  + 4194304;      // 262144 (wq; wkv adjacent)
  ushort_t* wkvB  = wqB   + 262144;       // 524288
  ushort_t* woutB = wkvB  + 524288;       // 262144
  ushort_t* wpw1B = woutB + 262144;       // 524288
  ushort_t* wpw2B = wpw1B + 524288;       // 262144
  ushort_t* q_h   = wpw2B + 262144;       // 4325376
  ushort_t* k_h   = q_h   + 4325376;      // 4456448
  ushort_t* v_h   = k_h   + 4456448;      // 4456448
  ushort_t* v_t   = v_h   + 4456448;      // 4456448
  ushort_t* attnb = v_t   + 4456448;      // 4325376
  ushort_t* outru_bf = attnb + 4325376;   // 4325376
  float*    wdwT  = (float*)(outru_bf + 4325376);   // 15872 f32
  ushort_t* glub  = q_h;                  // reuse q_h (dead after attn)
  ushort_t* zb    = attnb;                // reuse attnb (dead after out-proj)
  float* outp = (float*)d_out;

  const ushort_t* A_kv = memB;   // [mem | rc | utt] = 8704 rows

  Cvt9 ca;
  ca.s[0] = memry;                 ca.d[0] = memB;
  ca.s[1] = rctx;                  ca.d[1] = rcB;
  ca.s[2] = utter;                 ca.d[2] = uttB;
  ca.s[3] = (const float*)d_in[4]; ca.d[3] = wqB;
  ca.s[4] = (const float*)d_in[6]; ca.d[4] = wkvB;
  ca.s[5] = (const float*)d_in[8]; ca.d[5] = woutB;
  ca.s[6] = (const float*)d_in[10];ca.d[6] = wpw1B;
  ca.s[7] = (const float*)d_in[16];ca.d[7] = wpw2B;
  ca.wdw = w_dw; ca.wdwT = wdwT;
  int cnt[8] = {131072,131072,4194304,262144,524288,262144,524288,262144};
  int acc = 0;
  for (int i = 0; i < 8; ++i){ ca.bstart[i] = acc; acc += cnt[i] / 1024; }
  ca.bstart[8] = acc;
  cvt_f32_bf16<<<dim3(acc + 31), 256, 0, stream>>>(ca);

  // 1. fused qkv projection (N=1536, M=8704, NT=128) -> q_h / k_h / v_h
  gemm_bf16<4, 12, 128><<<dim3(8 * 9 * 12), 256, 0, stream>>>(
      A_kv, wqB, b_q, b_kv, nullptr, nullptr, q_h, k_h, v_h, 68);
  // 2. v transpose -> v_t [bh][dh][t]
  transpose_v<<<dim3(17, 64), 256, 0, stream>>>(v_h, v_t);
  // 3. attention (zero-staging) -> bf16 attnb
  attn_mfma<<<dim3(32, 64), 256, 0, stream>>>(q_h, k_h, v_t, lengths, attnb);
  // 4. out projection (NT=128, N=512) -> bf16 outru_bf
  gemm_bf16<0, 4, 128><<<dim3(8 * 9 * 4), 256, 0, stream>>>(
      attnb, woutB, b_out, nullptr, nullptr, nullptr, outru_bf, nullptr, nullptr, 66);
  // 5. pw1 + GLU -> bf16 glub
  gemm_pw1_glu<<<dim3(8 * 9 * 8), 256, 0, stream>>>(outru_bf, wpw1B, b_pw1, glub, 66);
  // 6. depthwise conv + LN + SiLU -> bf16 zb
  conv_ln_silu4<<<dim3(66, 8), 512, 0, stream>>>(glub, wdwT, b_dw, ln_g, ln_b, zb);
  // 7. pw2 + bf16 residual -> f32 out (NT=128)
  gemm_bf16<3, 4, 128><<<dim3(8 * 9 * 4), 256, 0, stream>>>(
      zb, wpw2B, b_pw2, nullptr, outru_bf, outp, nullptr, nullptr, nullptr, 66);
}